// Round 5
// baseline (119.461 us; speedup 1.0000x reference)
//
#include <hip/hip_runtime.h>
#include <math.h>

#define CDIM 1024
#define RDIM 100
#define NBAGS 8192

typedef float floatx4 __attribute__((ext_vector_type(4)));
typedef short bf16x8 __attribute__((ext_vector_type(8)));

__device__ __forceinline__ float dot4(float4 a, float4 b) {
    return a.x * b.x + a.y * b.y + a.z * b.z + a.w * b.w;
}

// fp32 -> bf16 round-to-nearest-even
__device__ __forceinline__ short f2bf(float f) {
    unsigned int u = __builtin_bit_cast(unsigned int, f);
    u += 0x7FFFu + ((u >> 16) & 1u);
    return (short)(u >> 16);
}

// Load two rows (8 x float4) into NAMED float4 registers.
#define LOADPAIR(d0q0, d0q1, d0q2, d0q3, d1q0, d1q1, d1q2, d1q3, r0i, r1i)   \
    {                                                                        \
        const float4* p0_ = (const float4*)(X + (size_t)(r0i) * CDIM);       \
        const float4* p1_ = (const float4*)(X + (size_t)(r1i) * CDIM);       \
        d0q0 = p0_[lane];       d0q1 = p0_[lane + 64];                       \
        d0q2 = p0_[lane + 128]; d0q3 = p0_[lane + 192];                      \
        d1q0 = p1_[lane];       d1q1 = p1_[lane + 64];                       \
        d1q2 = p1_[lane + 128]; d1q3 = p1_[lane + 192];                      \
    }

#define ACCQ(aq, xq0, xq1)                                                   \
    aq.x = fmaf(aq.x, corr, fmaf(w1, xq1.x, w0 * xq0.x));                    \
    aq.y = fmaf(aq.y, corr, fmaf(w1, xq1.y, w0 * xq0.y));                    \
    aq.z = fmaf(aq.z, corr, fmaf(w1, xq1.z, w0 * xq0.z));                    \
    aq.w = fmaf(aq.w, corr, fmaf(w1, xq1.w, w0 * xq0.w));

// Online-softmax merge of two rows held in named registers.
#define COMPUTE(x0q0, x0q1, x0q2, x0q3, x1q0, x1q1, x1q2, x1q3, row0, row1)  \
    {                                                                        \
        float p0 = dot4(x0q0, c0) + dot4(x0q1, c1)                           \
                 + dot4(x0q2, c2) + dot4(x0q3, c3);                          \
        float p1 = dot4(x1q0, c0) + dot4(x1q1, c1)                           \
                 + dot4(x1q2, c2) + dot4(x1q3, c3);                          \
        p0 += __shfl_xor(p0, 1);  p1 += __shfl_xor(p1, 1);                   \
        p0 += __shfl_xor(p0, 2);  p1 += __shfl_xor(p1, 2);                   \
        p0 += __shfl_xor(p0, 4);  p1 += __shfl_xor(p1, 4);                   \
        p0 += __shfl_xor(p0, 8);  p1 += __shfl_xor(p1, 8);                   \
        p0 += __shfl_xor(p0, 16); p1 += __shfl_xor(p1, 16);                  \
        p0 += __shfl_xor(p0, 32); p1 += __shfl_xor(p1, 32);                  \
        if ((row0) >= e) p0 = -INFINITY;                                     \
        if ((row1) >= e) p1 = -INFINITY;                                     \
        const float cm   = fmaxf(p0, p1);                                    \
        const float newm = fmaxf(m, cm);                                     \
        const float corr = __expf(m - newm);                                 \
        const float w0   = __expf(p0 - newm);                                \
        const float w1   = __expf(p1 - newm);                                \
        denom = fmaf(denom, corr, w0 + w1);                                  \
        m = newm;                                                            \
        ACCQ(acc0, x0q0, x1q0)                                               \
        ACCQ(acc1, x0q1, x1q1)                                               \
        ACCQ(acc2, x0q2, x1q2)                                               \
        ACCQ(acc3, x0q3, x1q3)                                               \
    }

// Kernel 1: one wave per bag, online softmax, X read once.
// Ping-pong register double-buffer (2 rows per half) with sched_barrier(0)
// pinning the prefetch loads ABOVE the compute, all buffers in NAMED float4
// vars so they are guaranteed VGPRs (rocprof round-3 showed VGPR=36: the
// array version never lived in registers).
__global__ __launch_bounds__(256) void bag_softmax_kernel(
    const float* __restrict__ X,
    const float* __restrict__ Constraints,
    const int* __restrict__ scope,
    const int* __restrict__ rel,
    float* __restrict__ bagbuf)
{
    const int wid  = threadIdx.x >> 6;
    const int lane = threadIdx.x & 63;
    const int bag  = blockIdx.x * 4 + wid;

    const int s = scope[2 * bag];
    const int e = scope[2 * bag + 1];
    const int r = rel[bag];

    float4 c0, c1, c2, c3;
    {
        const float4* conp = (const float4*)(Constraints + (size_t)r * CDIM);
        c0 = conp[lane];
        c1 = conp[lane + 64];
        c2 = conp[lane + 128];
        c3 = conp[lane + 192];
    }

    float4 acc0 = {0.f, 0.f, 0.f, 0.f};
    float4 acc1 = {0.f, 0.f, 0.f, 0.f};
    float4 acc2 = {0.f, 0.f, 0.f, 0.f};
    float4 acc3 = {0.f, 0.f, 0.f, 0.f};
    float m = -INFINITY;
    float denom = 0.f;

    // ping-pong buffers: A = rows {base, base+1}, B = rows {base+2, base+3}
    float4 A00, A01, A02, A03, A10, A11, A12, A13;
    float4 B00, B01, B02, B03, B10, B11, B12, B13;

    const int eM1 = e - 1;

    // prologue: load A = rows {s, s+1}
    {
        const int r1 = (s + 1 < e) ? (s + 1) : eM1;
        LOADPAIR(A00, A01, A02, A03, A10, A11, A12, A13, s, r1)
    }

    for (int base = s; base < e; base += 4) {
        // half 1: prefetch B = rows {base+2, base+3}; compute A
        {
            const int r0 = (base + 2 < e) ? (base + 2) : eM1;
            const int r1 = (base + 3 < e) ? (base + 3) : eM1;
            LOADPAIR(B00, B01, B02, B03, B10, B11, B12, B13, r0, r1)
        }
        __builtin_amdgcn_sched_barrier(0);
        COMPUTE(A00, A01, A02, A03, A10, A11, A12, A13, base, base + 1)

        // half 2: prefetch A = rows {base+4, base+5}; compute B
        {
            const int r0 = (base + 4 < e) ? (base + 4) : eM1;
            const int r1 = (base + 5 < e) ? (base + 5) : eM1;
            LOADPAIR(A00, A01, A02, A03, A10, A11, A12, A13, r0, r1)
        }
        __builtin_amdgcn_sched_barrier(0);
        COMPUTE(B00, B01, B02, B03, B10, B11, B12, B13, base + 2, base + 3)
    }

    const float inv = 1.0f / denom;
    float4* ob = (float4*)(bagbuf + (size_t)bag * CDIM);
    acc0.x *= inv; acc0.y *= inv; acc0.z *= inv; acc0.w *= inv;
    acc1.x *= inv; acc1.y *= inv; acc1.z *= inv; acc1.w *= inv;
    acc2.x *= inv; acc2.y *= inv; acc2.z *= inv; acc2.w *= inv;
    acc3.x *= inv; acc3.y *= inv; acc3.z *= inv; acc3.w *= inv;
    ob[lane]       = acc0;
    ob[lane + 64]  = acc1;
    ob[lane + 128] = acc2;
    ob[lane + 192] = acc3;
}

// Kernel 2 (unchanged): MFMA GEMM. out[b][r] = sum_c bag[b][c]*W[r][c] + bias[r].
__global__ __launch_bounds__(128) void bag_gemm_mfma(
    const float* __restrict__ bagbuf,
    const float* __restrict__ W,
    const float* __restrict__ bias,
    float* __restrict__ out)
{
    const int wid  = threadIdx.x >> 6;
    const int lane = threadIdx.x & 63;
    const int bag0 = (blockIdx.x * 2 + wid) * 16;
    const int ln15 = lane & 15;
    const int koff = (lane >> 4) * 8;

    floatx4 acc[7];
    #pragma unroll
    for (int t = 0; t < 7; ++t) acc[t] = (floatx4){0.f, 0.f, 0.f, 0.f};

    const float* aRow = bagbuf + (size_t)(bag0 + ln15) * CDIM + koff;

    for (int kc = 0; kc < CDIM / 32; ++kc) {
        const int k0 = kc * 32;

        float4 af0 = *(const float4*)(aRow + k0);
        float4 af1 = *(const float4*)(aRow + k0 + 4);
        bf16x8 aa;
        aa[0] = f2bf(af0.x); aa[1] = f2bf(af0.y); aa[2] = f2bf(af0.z); aa[3] = f2bf(af0.w);
        aa[4] = f2bf(af1.x); aa[5] = f2bf(af1.y); aa[6] = f2bf(af1.z); aa[7] = f2bf(af1.w);

        #pragma unroll
        for (int t = 0; t < 7; ++t) {
            const int r = t * 16 + ln15;
            bf16x8 b = (bf16x8)0;
            if (r < RDIM) {
                const float* wp = W + (size_t)r * CDIM + k0 + koff;
                float4 w0 = *(const float4*)(wp);
                float4 w1 = *(const float4*)(wp + 4);
                b[0] = f2bf(w0.x); b[1] = f2bf(w0.y); b[2] = f2bf(w0.z); b[3] = f2bf(w0.w);
                b[4] = f2bf(w1.x); b[5] = f2bf(w1.y); b[6] = f2bf(w1.z); b[7] = f2bf(w1.w);
            }
            acc[t] = __builtin_amdgcn_mfma_f32_16x16x32_bf16(aa, b, acc[t], 0, 0, 0);
        }
    }

    const int mbase = (lane >> 4) * 4;
    #pragma unroll
    for (int t = 0; t < 7; ++t) {
        const int r = t * 16 + ln15;
        if (r < RDIM) {
            const float bv = bias[r];
            #pragma unroll
            for (int reg = 0; reg < 4; ++reg) {
                const int bag = bag0 + mbase + reg;
                out[(size_t)bag * RDIM + r] = acc[t][reg] + bv;
            }
        }
    }
}

extern "C" void kernel_launch(void* const* d_in, const int* in_sizes, int n_in,
                              void* d_out, int out_size, void* d_ws, size_t ws_size,
                              hipStream_t stream) {
    const float* X    = (const float*)d_in[0];
    const float* Con  = (const float*)d_in[1];
    const float* W    = (const float*)d_in[2];
    const float* bias = (const float*)d_in[3];
    const int* scope  = (const int*)d_in[4];
    const int* rel    = (const int*)d_in[5];
    float* out = (float*)d_out;
    float* bagbuf = (float*)d_ws;   // NBAGS * CDIM * 4 = 33.6 MB

    bag_softmax_kernel<<<NBAGS / 4, 256, 0, stream>>>(X, Con, scope, rel, bagbuf);
    bag_gemm_mfma<<<NBAGS / 32, 128, 0, stream>>>(bagbuf, W, bias, out);
}

// Round 6
// 79.111 us; speedup vs baseline: 1.5101x; 1.5101x over previous
//
#include <hip/hip_runtime.h>
#include <math.h>

#define CDIM 1024
#define RDIM 100
#define NBAGS 8192

typedef float floatx4 __attribute__((ext_vector_type(4)));
typedef short bf16x8 __attribute__((ext_vector_type(8)));

__device__ __forceinline__ float dot4(float4 a, float4 b) {
    return a.x * b.x + a.y * b.y + a.z * b.z + a.w * b.w;
}

// fp32 -> bf16 round-to-nearest-even
__device__ __forceinline__ unsigned short f2bf(float f) {
    unsigned int u = __builtin_bit_cast(unsigned int, f);
    u += 0x7FFFu + ((u >> 16) & 1u);
    return (unsigned short)(u >> 16);
}

// Kernel 1: one BLOCK (4 waves) per bag. Rows striped across waves (stride 4),
// each wave holds its own online-softmax state (m, denom, 16-float acc) fully
// in registers; the 4 partial states merge once per bag through LDS.
// Blocks >= NBAGS instead convert one W row to bf16 (consumed by kernel 2,
// ordered by the stream).
__global__ __launch_bounds__(256) void bag_softmax_kernel(
    const float* __restrict__ X,
    const float* __restrict__ Constraints,
    const int* __restrict__ scope,
    const int* __restrict__ rel,
    const float* __restrict__ W,
    unsigned short* __restrict__ bagbuf,
    unsigned short* __restrict__ Wbf)
{
    const int lane = threadIdx.x & 63;
    const int w    = threadIdx.x >> 6;

    if (blockIdx.x >= NBAGS) {
        // W fp32 -> bf16 conversion: one row per block, 4 elems per thread.
        const int rr = blockIdx.x - NBAGS;
        const int t  = threadIdx.x;
        float4 v = *(const float4*)(W + (size_t)rr * CDIM + t * 4);
        ushort4 o;
        o.x = f2bf(v.x); o.y = f2bf(v.y); o.z = f2bf(v.z); o.w = f2bf(v.w);
        *(ushort4*)(Wbf + (size_t)rr * CDIM + t * 4) = o;
        return;
    }

    __shared__ float4 lds_acc[4][256];
    __shared__ float  lds_m[4];
    __shared__ float  lds_d[4];

    const int bag = blockIdx.x;
    const int s = scope[2 * bag];
    const int e = scope[2 * bag + 1];
    const int r = rel[bag];

    const float4* conp = (const float4*)(Constraints + (size_t)r * CDIM);
    const float4 c0 = conp[lane];
    const float4 c1 = conp[lane + 64];
    const float4 c2 = conp[lane + 128];
    const float4 c3 = conp[lane + 192];

    float4 a0 = {0.f, 0.f, 0.f, 0.f};
    float4 a1 = {0.f, 0.f, 0.f, 0.f};
    float4 a2 = {0.f, 0.f, 0.f, 0.f};
    float4 a3 = {0.f, 0.f, 0.f, 0.f};
    float m = -INFINITY;
    float denom = 0.f;

    int row = s + w;
    if (row < e) {                    // uniform per wave
        const float4* xp = (const float4*)(X + (size_t)row * CDIM);
        float4 A0 = xp[lane];
        float4 A1 = xp[lane + 64];
        float4 A2 = xp[lane + 128];
        float4 A3 = xp[lane + 192];

        for (; row < e; row += 4) {
            // prefetch next row (clamped: last iter re-reads -> L1 hit)
            const int nxt = (row + 4 < e) ? (row + 4) : row;
            const float4* np = (const float4*)(X + (size_t)nxt * CDIM);
            float4 B0 = np[lane];
            float4 B1 = np[lane + 64];
            float4 B2 = np[lane + 128];
            float4 B3 = np[lane + 192];
            __builtin_amdgcn_sched_barrier(0);

            float p = dot4(A0, c0) + dot4(A1, c1) + dot4(A2, c2) + dot4(A3, c3);
            p += __shfl_xor(p, 1);
            p += __shfl_xor(p, 2);
            p += __shfl_xor(p, 4);
            p += __shfl_xor(p, 8);
            p += __shfl_xor(p, 16);
            p += __shfl_xor(p, 32);

            const float newm = fmaxf(m, p);
            const float corr = __expf(m - newm);   // 0 on first row
            const float wgt  = __expf(p - newm);
            denom = fmaf(denom, corr, wgt);
            a0.x = fmaf(a0.x, corr, wgt * A0.x); a0.y = fmaf(a0.y, corr, wgt * A0.y);
            a0.z = fmaf(a0.z, corr, wgt * A0.z); a0.w = fmaf(a0.w, corr, wgt * A0.w);
            a1.x = fmaf(a1.x, corr, wgt * A1.x); a1.y = fmaf(a1.y, corr, wgt * A1.y);
            a1.z = fmaf(a1.z, corr, wgt * A1.z); a1.w = fmaf(a1.w, corr, wgt * A1.w);
            a2.x = fmaf(a2.x, corr, wgt * A2.x); a2.y = fmaf(a2.y, corr, wgt * A2.y);
            a2.z = fmaf(a2.z, corr, wgt * A2.z); a2.w = fmaf(a2.w, corr, wgt * A2.w);
            a3.x = fmaf(a3.x, corr, wgt * A3.x); a3.y = fmaf(a3.y, corr, wgt * A3.y);
            a3.z = fmaf(a3.z, corr, wgt * A3.z); a3.w = fmaf(a3.w, corr, wgt * A3.w);
            m = newm;

            A0 = B0; A1 = B1; A2 = B2; A3 = B3;
        }
    }

    if (lane == 0) { lds_m[w] = m; lds_d[w] = denom; }
    lds_acc[w][lane]       = a0;
    lds_acc[w][lane + 64]  = a1;
    lds_acc[w][lane + 128] = a2;
    lds_acc[w][lane + 192] = a3;
    __syncthreads();

    // merge 4 partial online-softmax states; each thread owns one float4 slot
    const int t = threadIdx.x;
    const float m0 = lds_m[0], m1 = lds_m[1], m2 = lds_m[2], m3 = lds_m[3];
    const float ms = fmaxf(fmaxf(m0, m1), fmaxf(m2, m3));   // finite: every bag has >=1 row
    const float f0 = __expf(m0 - ms);   // empty wave: exp(-inf) = 0
    const float f1 = __expf(m1 - ms);
    const float f2 = __expf(m2 - ms);
    const float f3 = __expf(m3 - ms);
    const float dn = f0 * lds_d[0] + f1 * lds_d[1] + f2 * lds_d[2] + f3 * lds_d[3];
    const float inv = 1.0f / dn;

    const float4 v0 = lds_acc[0][t];
    const float4 v1 = lds_acc[1][t];
    const float4 v2 = lds_acc[2][t];
    const float4 v3 = lds_acc[3][t];
    const float ox = (f0 * v0.x + f1 * v1.x + f2 * v2.x + f3 * v3.x) * inv;
    const float oy = (f0 * v0.y + f1 * v1.y + f2 * v2.y + f3 * v3.y) * inv;
    const float oz = (f0 * v0.z + f1 * v1.z + f2 * v2.z + f3 * v3.z) * inv;
    const float ow = (f0 * v0.w + f1 * v1.w + f2 * v2.w + f3 * v3.w) * inv;

    ushort4 o;
    o.x = f2bf(ox); o.y = f2bf(oy); o.z = f2bf(oz); o.w = f2bf(ow);
    *(ushort4*)(bagbuf + (size_t)bag * CDIM + t * 4) = o;
}

// Kernel 2: MFMA GEMM, bf16 A (bagbuf) and bf16 B (pre-converted W).
// out[b][r] = sum_c bag[b][c]*W[r][c] + bias[r].
// A-frag: lane&15 = bag row, k = (lane>>4)*8 + i
// B-frag: lane&15 = r col,   k = (lane>>4)*8 + i
// D:      col = lane&15 (r), row = (lane>>4)*4 + reg (bag)
__global__ __launch_bounds__(128) void bag_gemm_mfma(
    const unsigned short* __restrict__ bagbuf,
    const unsigned short* __restrict__ Wbf,
    const float* __restrict__ bias,
    float* __restrict__ out)
{
    const int wid  = threadIdx.x >> 6;
    const int lane = threadIdx.x & 63;
    const int bag0 = (blockIdx.x * 2 + wid) * 16;
    const int ln15 = lane & 15;
    const int koff = (lane >> 4) * 8;

    floatx4 acc[7];
    #pragma unroll
    for (int t = 0; t < 7; ++t) acc[t] = (floatx4){0.f, 0.f, 0.f, 0.f};

    const unsigned short* aRow = bagbuf + (size_t)(bag0 + ln15) * CDIM + koff;
    const int rB = ln15;   // column within each 16-wide r-tile

    for (int kc = 0; kc < CDIM / 32; ++kc) {
        const int k0 = kc * 32;
        const bf16x8 a = *(const bf16x8*)(aRow + k0);

        #pragma unroll
        for (int t = 0; t < 7; ++t) {
            const int r = t * 16 + rB;
            bf16x8 b = (bf16x8)0;
            if (r < RDIM) {
                b = *(const bf16x8*)(Wbf + (size_t)r * CDIM + k0 + koff);
            }
            acc[t] = __builtin_amdgcn_mfma_f32_16x16x32_bf16(a, b, acc[t], 0, 0, 0);
        }
    }

    const int mbase = (lane >> 4) * 4;
    #pragma unroll
    for (int t = 0; t < 7; ++t) {
        const int r = t * 16 + rB;
        if (r < RDIM) {
            const float bv = bias[r];
            #pragma unroll
            for (int reg = 0; reg < 4; ++reg) {
                const int bag = bag0 + mbase + reg;
                out[(size_t)bag * RDIM + r] = acc[t][reg] + bv;
            }
        }
    }
}

extern "C" void kernel_launch(void* const* d_in, const int* in_sizes, int n_in,
                              void* d_out, int out_size, void* d_ws, size_t ws_size,
                              hipStream_t stream) {
    const float* X    = (const float*)d_in[0];
    const float* Con  = (const float*)d_in[1];
    const float* W    = (const float*)d_in[2];
    const float* bias = (const float*)d_in[3];
    const int* scope  = (const int*)d_in[4];
    const int* rel    = (const int*)d_in[5];
    float* out = (float*)d_out;

    unsigned short* bagbuf = (unsigned short*)d_ws;          // 8192*1024*2 = 16.8 MB
    unsigned short* Wbf    = bagbuf + (size_t)NBAGS * CDIM;  // 100*1024*2  = 0.2 MB

    bag_softmax_kernel<<<NBAGS + RDIM, 256, 0, stream>>>(X, Con, scope, rel, W, bagbuf, Wbf);
    bag_gemm_mfma<<<NBAGS / 32, 128, 0, stream>>>(bagbuf, Wbf, bias, out);
}

// Round 7
// 72.256 us; speedup vs baseline: 1.6533x; 1.0949x over previous
//
#include <hip/hip_runtime.h>
#include <math.h>

#define CDIM 1024
#define RDIM 100
#define NBAGS 8192

typedef float floatx4 __attribute__((ext_vector_type(4)));
typedef short bf16x8 __attribute__((ext_vector_type(8)));

__device__ __forceinline__ float dot4(float4 a, float4 b) {
    return a.x * b.x + a.y * b.y + a.z * b.z + a.w * b.w;
}

// fp32 -> bf16 round-to-nearest-even
__device__ __forceinline__ unsigned short f2bf(float f) {
    unsigned int u = __builtin_bit_cast(unsigned int, f);
    u += 0x7FFFu + ((u >> 16) & 1u);
    return (unsigned short)(u >> 16);
}

// Kernel 1 (UNCHANGED from round 6): one BLOCK (4 waves) per bag, rows striped
// across waves, per-wave online-softmax state in registers, LDS merge.
// Blocks >= NBAGS convert W rows to bf16 for kernel 2.
__global__ __launch_bounds__(256) void bag_softmax_kernel(
    const float* __restrict__ X,
    const float* __restrict__ Constraints,
    const int* __restrict__ scope,
    const int* __restrict__ rel,
    const float* __restrict__ W,
    unsigned short* __restrict__ bagbuf,
    unsigned short* __restrict__ Wbf)
{
    const int lane = threadIdx.x & 63;
    const int w    = threadIdx.x >> 6;

    if (blockIdx.x >= NBAGS) {
        const int rr = blockIdx.x - NBAGS;
        const int t  = threadIdx.x;
        float4 v = *(const float4*)(W + (size_t)rr * CDIM + t * 4);
        ushort4 o;
        o.x = f2bf(v.x); o.y = f2bf(v.y); o.z = f2bf(v.z); o.w = f2bf(v.w);
        *(ushort4*)(Wbf + (size_t)rr * CDIM + t * 4) = o;
        return;
    }

    __shared__ float4 lds_acc[4][256];
    __shared__ float  lds_m[4];
    __shared__ float  lds_d[4];

    const int bag = blockIdx.x;
    const int s = scope[2 * bag];
    const int e = scope[2 * bag + 1];
    const int r = rel[bag];

    const float4* conp = (const float4*)(Constraints + (size_t)r * CDIM);
    const float4 c0 = conp[lane];
    const float4 c1 = conp[lane + 64];
    const float4 c2 = conp[lane + 128];
    const float4 c3 = conp[lane + 192];

    float4 a0 = {0.f, 0.f, 0.f, 0.f};
    float4 a1 = {0.f, 0.f, 0.f, 0.f};
    float4 a2 = {0.f, 0.f, 0.f, 0.f};
    float4 a3 = {0.f, 0.f, 0.f, 0.f};
    float m = -INFINITY;
    float denom = 0.f;

    int row = s + w;
    if (row < e) {                    // uniform per wave
        const float4* xp = (const float4*)(X + (size_t)row * CDIM);
        float4 A0 = xp[lane];
        float4 A1 = xp[lane + 64];
        float4 A2 = xp[lane + 128];
        float4 A3 = xp[lane + 192];

        for (; row < e; row += 4) {
            const int nxt = (row + 4 < e) ? (row + 4) : row;
            const float4* np = (const float4*)(X + (size_t)nxt * CDIM);
            float4 B0 = np[lane];
            float4 B1 = np[lane + 64];
            float4 B2 = np[lane + 128];
            float4 B3 = np[lane + 192];
            __builtin_amdgcn_sched_barrier(0);

            float p = dot4(A0, c0) + dot4(A1, c1) + dot4(A2, c2) + dot4(A3, c3);
            p += __shfl_xor(p, 1);
            p += __shfl_xor(p, 2);
            p += __shfl_xor(p, 4);
            p += __shfl_xor(p, 8);
            p += __shfl_xor(p, 16);
            p += __shfl_xor(p, 32);

            const float newm = fmaxf(m, p);
            const float corr = __expf(m - newm);   // 0 on first row
            const float wgt  = __expf(p - newm);
            denom = fmaf(denom, corr, wgt);
            a0.x = fmaf(a0.x, corr, wgt * A0.x); a0.y = fmaf(a0.y, corr, wgt * A0.y);
            a0.z = fmaf(a0.z, corr, wgt * A0.z); a0.w = fmaf(a0.w, corr, wgt * A0.w);
            a1.x = fmaf(a1.x, corr, wgt * A1.x); a1.y = fmaf(a1.y, corr, wgt * A1.y);
            a1.z = fmaf(a1.z, corr, wgt * A1.z); a1.w = fmaf(a1.w, corr, wgt * A1.w);
            a2.x = fmaf(a2.x, corr, wgt * A2.x); a2.y = fmaf(a2.y, corr, wgt * A2.y);
            a2.z = fmaf(a2.z, corr, wgt * A2.z); a2.w = fmaf(a2.w, corr, wgt * A2.w);
            a3.x = fmaf(a3.x, corr, wgt * A3.x); a3.y = fmaf(a3.y, corr, wgt * A3.y);
            a3.z = fmaf(a3.z, corr, wgt * A3.z); a3.w = fmaf(a3.w, corr, wgt * A3.w);
            m = newm;

            A0 = B0; A1 = B1; A2 = B2; A3 = B3;
        }
    }

    if (lane == 0) { lds_m[w] = m; lds_d[w] = denom; }
    lds_acc[w][lane]       = a0;
    lds_acc[w][lane + 64]  = a1;
    lds_acc[w][lane + 128] = a2;
    lds_acc[w][lane + 192] = a3;
    __syncthreads();

    const int t = threadIdx.x;
    const float m0 = lds_m[0], m1 = lds_m[1], m2 = lds_m[2], m3 = lds_m[3];
    const float ms = fmaxf(fmaxf(m0, m1), fmaxf(m2, m3));
    const float f0 = __expf(m0 - ms);
    const float f1 = __expf(m1 - ms);
    const float f2 = __expf(m2 - ms);
    const float f3 = __expf(m3 - ms);
    const float dn = f0 * lds_d[0] + f1 * lds_d[1] + f2 * lds_d[2] + f3 * lds_d[3];
    const float inv = 1.0f / dn;

    const float4 v0 = lds_acc[0][t];
    const float4 v1 = lds_acc[1][t];
    const float4 v2 = lds_acc[2][t];
    const float4 v3 = lds_acc[3][t];
    const float ox = (f0 * v0.x + f1 * v1.x + f2 * v2.x + f3 * v3.x) * inv;
    const float oy = (f0 * v0.y + f1 * v1.y + f2 * v2.y + f3 * v3.y) * inv;
    const float oz = (f0 * v0.z + f1 * v1.z + f2 * v2.z + f3 * v3.z) * inv;
    const float ow = (f0 * v0.w + f1 * v1.w + f2 * v2.w + f3 * v3.w) * inv;

    ushort4 o;
    o.x = f2bf(ox); o.y = f2bf(oy); o.z = f2bf(oz); o.w = f2bf(ow);
    *(ushort4*)(bagbuf + (size_t)bag * CDIM + t * 4) = o;
}

// Kernel 2: MFMA GEMM with split-K x4. One block (4 waves) per 16-bag tile;
// wave q computes K-chunk [q*256, q*256+256); partials combined via LDS.
// Round-6 version had 512 waves on 1024 SIMDs (half idle, 1 wave each) ->
// latency-bound. This gives 2048 waves (2/SIMD) with 4x less serial work.
__global__ __launch_bounds__(256) void bag_gemm_mfma(
    const unsigned short* __restrict__ bagbuf,
    const unsigned short* __restrict__ Wbf,
    const float* __restrict__ bias,
    float* __restrict__ out)
{
    const int q    = threadIdx.x >> 6;   // k-chunk 0..3
    const int lane = threadIdx.x & 63;
    const int bag0 = blockIdx.x * 16;
    const int ln15 = lane & 15;
    const int koff = (lane >> 4) * 8;

    __shared__ floatx4 lds[4][7][64];    // 28 KB

    floatx4 acc[7];
    #pragma unroll
    for (int t = 0; t < 7; ++t) acc[t] = (floatx4){0.f, 0.f, 0.f, 0.f};

    const unsigned short* aRow = bagbuf + (size_t)(bag0 + ln15) * CDIM + koff;

    #pragma unroll
    for (int i = 0; i < 8; ++i) {
        const int k0 = (q * 8 + i) * 32;
        const bf16x8 a = *(const bf16x8*)(aRow + k0);

        #pragma unroll
        for (int t = 0; t < 7; ++t) {
            const int r = t * 16 + ln15;
            bf16x8 b = (bf16x8)0;
            if (r < RDIM) {
                b = *(const bf16x8*)(Wbf + (size_t)r * CDIM + k0 + koff);
            }
            acc[t] = __builtin_amdgcn_mfma_f32_16x16x32_bf16(a, b, acc[t], 0, 0, 0);
        }
    }

    #pragma unroll
    for (int t = 0; t < 7; ++t) lds[q][t][lane] = acc[t];
    __syncthreads();

    // 7*64 = 448 (t,slot) pairs; thread i handles pairs i and i+256.
    #pragma unroll
    for (int p = threadIdx.x; p < 448; p += 256) {
        const int t    = p >> 6;
        const int slot = p & 63;
        const int r    = t * 16 + (slot & 15);
        if (r < RDIM) {
            floatx4 s = lds[0][t][slot];
            s += lds[1][t][slot];
            s += lds[2][t][slot];
            s += lds[3][t][slot];
            const float bv = bias[r];
            const int bagr = bag0 + (slot >> 4) * 4;
            out[(size_t)(bagr + 0) * RDIM + r] = s[0] + bv;
            out[(size_t)(bagr + 1) * RDIM + r] = s[1] + bv;
            out[(size_t)(bagr + 2) * RDIM + r] = s[2] + bv;
            out[(size_t)(bagr + 3) * RDIM + r] = s[3] + bv;
        }
    }
}

extern "C" void kernel_launch(void* const* d_in, const int* in_sizes, int n_in,
                              void* d_out, int out_size, void* d_ws, size_t ws_size,
                              hipStream_t stream) {
    const float* X    = (const float*)d_in[0];
    const float* Con  = (const float*)d_in[1];
    const float* W    = (const float*)d_in[2];
    const float* bias = (const float*)d_in[3];
    const int* scope  = (const int*)d_in[4];
    const int* rel    = (const int*)d_in[5];
    float* out = (float*)d_out;

    unsigned short* bagbuf = (unsigned short*)d_ws;          // 8192*1024*2 = 16.8 MB
    unsigned short* Wbf    = bagbuf + (size_t)NBAGS * CDIM;  // 100*1024*2  = 0.2 MB

    bag_softmax_kernel<<<NBAGS + RDIM, 256, 0, stream>>>(X, Con, scope, rel, W, bagbuf, Wbf);
    bag_gemm_mfma<<<NBAGS / 16, 256, 0, stream>>>(bagbuf, Wbf, bias, out);
}